// Round 1
// baseline (1068.025 us; speedup 1.0000x reference)
//
#include <hip/hip_runtime.h>
#include <hip/hip_bf16.h>
#include <math.h>

#define BB 64
#define SS 2048
#define EE 1024      // ENC = DEC
#define AA 1024      // ATTN
#define MT (SS*BB)   // 131072 rows of the big GEMM

typedef __attribute__((ext_vector_type(4))) float f4;
typedef __attribute__((ext_vector_type(8))) short s8;

__device__ __forceinline__ unsigned short f2bf(float x) {
  union { float f; unsigned u; } v; v.f = x;
  unsigned r = v.u + 0x7FFFu + ((v.u >> 16) & 1u);   // RNE
  return (unsigned short)(r >> 16);
}

// ---- convert We (rows of attn_w_weight[:, :1024], stride 2048) to packed bf16 (1024x1024)
__global__ void k_convW(const float* __restrict__ w, unsigned short* __restrict__ wb) {
  int i0 = blockIdx.x * 1024 + threadIdx.x;
  #pragma unroll
  for (int k = 0; k < 4; ++k) {
    int i = i0 + k * 256;
    int a = i >> 10, e = i & 1023;
    wb[i] = f2bf(w[a * 2048 + e]);
  }
}

// ---- hp[b][a] = hidden[b,:]·Wd[a,:] + bias[a]   (f32, tiny)
__global__ void k_hp(const float* __restrict__ hidden, const float* __restrict__ w,
                     const float* __restrict__ wbias, float* __restrict__ hp) {
  __shared__ float hs[1024];
  int b = blockIdx.x, tid = threadIdx.x;
  for (int i = tid; i < 1024; i += 256) hs[i] = hidden[b * 1024 + i];
  __syncthreads();
  int a = blockIdx.y * 256 + tid;
  const f4* wd = (const f4*)(w + a * 2048 + 1024);
  const f4* hv = (const f4*)hs;
  float acc = wbias[a];
  #pragma unroll 8
  for (int d = 0; d < 256; ++d) {
    f4 x = wd[d], y = hv[d];
    acc += x[0]*y[0] + x[1]*y[1] + x[2]*y[2] + x[3]*y[3];
  }
  hp[b * 1024 + a] = acc;
}

#define GLD16(gp, lp) __builtin_amdgcn_global_load_lds( \
    (const __attribute__((address_space(1))) void*)(gp), \
    (__attribute__((address_space(3))) void*)(lp), 16, 0, 0)

// ---- big fused GEMM: X = A(131072x1024 f32->bf16) * We^T, epilogue tanh(X+hp)+vw-dot
// partials[p][b][s], p = bn*2 + wave_col  (16 partials of the a-reduction)
__global__ __launch_bounds__(256) void k_gemm(
    const float* __restrict__ A, const unsigned short* __restrict__ Wb,
    const float* __restrict__ hp, const float* __restrict__ vw,
    float* __restrict__ part) {
  __shared__ unsigned short lA[2][128 * 32];
  __shared__ unsigned short lB[2][128 * 32];
  int bid = blockIdx.x;
  // XCD swizzle: the 8 bn-blocks of one bm land on the same XCD within a 64-block window
  int bm = ((bid >> 6) << 3) | (bid & 7);
  int bn = (bid >> 3) & 7;
  int tid = threadIdx.x, lane = tid & 63;
  int wid = tid >> 6, wr = wid >> 1, wc = wid & 1;

  int arow = tid >> 1, ahalf = tid & 1;
  const float* aptr = A + (size_t)(bm * 128 + arow) * 1024 + ahalf * 16;

  f4 areg[4];
  f4 acc[4][4];
  f4 z = {0.f, 0.f, 0.f, 0.f};
  #pragma unroll
  for (int i = 0; i < 4; ++i)
    #pragma unroll
    for (int j = 0; j < 4; ++j) acc[i][j] = z;

  auto stageA_load = [&](int t) {
    const f4* p = (const f4*)(aptr + t * 32);
    areg[0] = p[0]; areg[1] = p[1]; areg[2] = p[2]; areg[3] = p[3];
  };
  auto stageB = [&](int buf, int t) {
    #pragma unroll
    for (int j = 0; j < 2; ++j) {
      int i = tid + j * 256;
      int row = i >> 2, kqp = i & 3;
      int kql = kqp ^ (row & 3);                     // pre-swizzled global source
      const unsigned short* src = Wb + (size_t)(bn * 128 + row) * 1024 + t * 32 + kql * 8;
      GLD16(src, &lB[buf][i * 8]);                   // linear LDS dest
    }
  };
  auto stageA_write = [&](int buf) {
    s8 w0, w1;
    const float* af = (const float*)areg;
    #pragma unroll
    for (int i = 0; i < 8; ++i) { w0[i] = (short)f2bf(af[i]); w1[i] = (short)f2bf(af[8 + i]); }
    int k0 = ahalf * 2;
    *(s8*)&lA[buf][arow * 32 + (((k0    ) ^ (arow & 3)) << 3)] = w0;
    *(s8*)&lA[buf][arow * 32 + (((k0 + 1) ^ (arow & 3)) << 3)] = w1;
  };
  auto compute = [&](int buf) {
    s8 af_[4], bf_[4];
    int kq = lane >> 4, c = lane & 15;
    #pragma unroll
    for (int mi = 0; mi < 4; ++mi) {
      int row = wr * 64 + mi * 16 + c;
      af_[mi] = *(const s8*)&lA[buf][row * 32 + ((kq ^ (row & 3)) << 3)];
    }
    #pragma unroll
    for (int ni = 0; ni < 4; ++ni) {
      int row = wc * 64 + ni * 16 + c;
      bf_[ni] = *(const s8*)&lB[buf][row * 32 + ((kq ^ (row & 3)) << 3)];
    }
    #pragma unroll
    for (int mi = 0; mi < 4; ++mi)
      #pragma unroll
      for (int ni = 0; ni < 4; ++ni)
        acc[mi][ni] = __builtin_amdgcn_mfma_f32_16x16x32_bf16(af_[mi], bf_[ni], acc[mi][ni], 0, 0, 0);
  };

  stageA_load(0);
  stageB(0, 0);
  stageA_write(0);
  __syncthreads();
  for (int t = 0; t < 32; ++t) {
    int buf = t & 1;
    if (t < 31) { stageA_load(t + 1); stageB(buf ^ 1, t + 1); }
    compute(buf);
    if (t < 31) stageA_write(buf ^ 1);
    __syncthreads();
  }

  // epilogue: t = tanh(x + hp[b][a]) * vw[a]; reduce over the 64 a-columns of this wave
  int c = lane & 15, lg = lane >> 4;
  int colBase = bn * 128 + wc * 64 + c;
  float rs[4][4];
  #pragma unroll
  for (int mi = 0; mi < 4; ++mi)
    #pragma unroll
    for (int j = 0; j < 4; ++j) rs[mi][j] = 0.f;
  #pragma unroll
  for (int ni = 0; ni < 4; ++ni) {
    int a = colBase + ni * 16;
    float vwa = vw[a];
    const float* hpa = hp + a;
    #pragma unroll
    for (int mi = 0; mi < 4; ++mi) {
      #pragma unroll
      for (int j = 0; j < 4; ++j) {
        int r = wr * 64 + mi * 16 + lg * 4 + j;
        int b = r & 63;                           // row%64 (bm*128 ≡ 0 mod 64)
        float x = acc[mi][ni][j] + hpa[b * 1024];
        rs[mi][j] += tanhf(x) * vwa;
      }
    }
  }
  #pragma unroll
  for (int off = 1; off < 16; off <<= 1) {
    #pragma unroll
    for (int mi = 0; mi < 4; ++mi)
      #pragma unroll
      for (int j = 0; j < 4; ++j)
        rs[mi][j] += __shfl_xor(rs[mi][j], off, 64);
  }
  if ((lane & 15) == 0) {
    int p = bn * 2 + wc;
    #pragma unroll
    for (int mi = 0; mi < 4; ++mi)
      #pragma unroll
      for (int j = 0; j < 4; ++j) {
        int m = bm * 128 + wr * 64 + mi * 16 + lg * 4 + j;
        int b = m & 63, s = m >> 6;
        part[(size_t)p * MT + b * SS + s] = rs[mi][j];
      }
  }
}

// ---- sum 16 partials -> scores, softmax over s per b -> weights[b][s]
__global__ void k_softmax(const float* __restrict__ part, float* __restrict__ wt) {
  int b = blockIdx.x, tid = threadIdx.x, lane = tid & 63, wid = tid >> 6;
  __shared__ float red[8];
  float sc[8];
  float mx = -1e30f;
  #pragma unroll
  for (int i = 0; i < 8; ++i) {
    int s = tid + i * 256;
    float a = 0.f;
    #pragma unroll
    for (int p = 0; p < 16; ++p) a += part[(size_t)p * MT + b * SS + s];
    sc[i] = a; mx = fmaxf(mx, a);
  }
  for (int o = 1; o < 64; o <<= 1) mx = fmaxf(mx, __shfl_xor(mx, o, 64));
  if (lane == 0) red[wid] = mx;
  __syncthreads();
  mx = fmaxf(fmaxf(red[0], red[1]), fmaxf(red[2], red[3]));
  float sum = 0.f;
  #pragma unroll
  for (int i = 0; i < 8; ++i) { sc[i] = expf(sc[i] - mx); sum += sc[i]; }
  for (int o = 1; o < 64; o <<= 1) sum += __shfl_xor(sum, o, 64);
  if (lane == 0) red[4 + wid] = sum;
  __syncthreads();
  sum = red[4] + red[5] + red[6] + red[7];
  float inv = 1.f / sum;
  #pragma unroll
  for (int i = 0; i < 8; ++i) wt[b * SS + tid + i * 256] = sc[i] * inv;
}

// ---- context partials: ctxp[cch][b][e] = sum_{s in chunk} w[b][s] * v[s][b][e]
__global__ void k_ctx(const float* __restrict__ v, const float* __restrict__ wt,
                      float* __restrict__ ctxp) {
  int b = blockIdx.x, cch = blockIdx.y, tid = threadIdx.x;
  f4 acc = {0.f, 0.f, 0.f, 0.f};
  int s0 = cch * 128;
  const float* wrow = wt + b * SS;
  #pragma unroll 4
  for (int s = s0; s < s0 + 128; ++s) {
    float ws = wrow[s];
    const f4* vp = (const f4*)(v + (size_t)(s * 64 + b) * 1024);
    acc += vp[tid] * ws;
  }
  *(f4*)(ctxp + (size_t)(cch * 64 + b) * 1024 + tid * 4) = acc;
}

__global__ void k_out(const float* __restrict__ ctxp, float* __restrict__ out) {
  int b = blockIdx.x, tid = threadIdx.x;
  f4 acc = {0.f, 0.f, 0.f, 0.f};
  #pragma unroll
  for (int cch = 0; cch < 16; ++cch)
    acc += *(const f4*)(ctxp + (size_t)(cch * 64 + b) * 1024 + tid * 4);
  *(f4*)(out + b * 1024 + tid * 4) = acc;
}

extern "C" void kernel_launch(void* const* d_in, const int* in_sizes, int n_in,
                              void* d_out, int out_size, void* d_ws, size_t ws_size,
                              hipStream_t stream) {
  const float* hidden = (const float*)d_in[0];
  const float* v      = (const float*)d_in[1];   // (S, B, ENC) = (131072, 1024) rows s*64+b
  const float* ww     = (const float*)d_in[2];   // (1024, 2048)
  const float* wbias  = (const float*)d_in[3];   // (1024)
  const float* vwgt   = (const float*)d_in[4];   // (1, 1024)
  // d_in[5] attn_v_bias: softmax shift-invariant, dropped
  float* out = (float*)d_out;

  char* ws = (char*)d_ws;
  float*          hp   = (float*)(ws);                                   // 256 KB
  unsigned short* wb   = (unsigned short*)(ws + 262144);                 // 2 MB
  float*          part = (float*)(ws + 262144 + 2097152);                // 8 MB
  float*          wt   = (float*)(ws + 262144 + 2097152 + 8388608);      // 512 KB
  float*          ctxp = (float*)(ws + 262144 + 2097152 + 8388608 + 524288); // 4 MB

  k_convW<<<1024, 256, 0, stream>>>(ww, wb);
  k_hp<<<dim3(64, 4), 256, 0, stream>>>(hidden, ww, wbias, hp);
  k_gemm<<<8192, 256, 0, stream>>>(v, wb, hp, vwgt, part);
  k_softmax<<<64, 256, 0, stream>>>(part, wt);
  k_ctx<<<dim3(64, 16), 256, 0, stream>>>(v, wt, ctxp);
  k_out<<<64, 256, 0, stream>>>(ctxp, out);
}

// Round 2
// 638.203 us; speedup vs baseline: 1.6735x; 1.6735x over previous
//
#include <hip/hip_runtime.h>
#include <hip/hip_bf16.h>
#include <math.h>

#define BB 64
#define SS 2048
#define EE 1024      // ENC = DEC
#define AA 1024      // ATTN
#define MT (SS*BB)   // 131072 rows of the big GEMM

typedef __attribute__((ext_vector_type(4))) float f4;
typedef __attribute__((ext_vector_type(8))) short s8;

__device__ __forceinline__ unsigned short f2bf(float x) {
  union { float f; unsigned u; } v; v.f = x;
  unsigned r = v.u + 0x7FFFu + ((v.u >> 16) & 1u);   // RNE
  return (unsigned short)(r >> 16);
}
__device__ __forceinline__ float bf2f(unsigned short x) {
  union { unsigned u; float f; } v; v.u = ((unsigned)x) << 16;
  return v.f;
}
__device__ __forceinline__ float fast_tanh(float x) {
  // tanh(x) = 1 - 2/(e^{2x}+1); __expf -> v_exp_f32, rcp -> v_rcp_f32
  float t = __expf(2.0f * x);
  return 1.0f - 2.0f * __builtin_amdgcn_rcpf(t + 1.0f);
}

// ---- convert We (rows of attn_w_weight[:, :1024], stride 2048) to packed bf16 (1024x1024)
__global__ void k_convW(const float* __restrict__ w, unsigned short* __restrict__ wb) {
  int i0 = blockIdx.x * 1024 + threadIdx.x;
  #pragma unroll
  for (int k = 0; k < 4; ++k) {
    int i = i0 + k * 256;
    int a = i >> 10, e = i & 1023;
    wb[i] = f2bf(w[a * 2048 + e]);
  }
}

// ---- convert a chunk of v (f32) to packed bf16: rows [r0, r0+nr) of (131072 x 1024)
__global__ void k_convV(const float* __restrict__ v, unsigned short* __restrict__ vb,
                        int r0) {
  // each block: 256 threads x 128 elems = 32768 elems; elem index within chunk
  size_t base = (size_t)blockIdx.x * 32768 + (size_t)threadIdx.x * 8;
  const float* src = v + (size_t)r0 * 1024;
  #pragma unroll 4
  for (int it = 0; it < 16; ++it) {
    size_t i = base + (size_t)it * 2048;
    f4 x0 = *(const f4*)(src + i);
    f4 x1 = *(const f4*)(src + i + 4);
    s8 o;
    #pragma unroll
    for (int j = 0; j < 4; ++j) { o[j] = (short)f2bf(x0[j]); o[4 + j] = (short)f2bf(x1[j]); }
    *(s8*)(vb + i) = o;
  }
}

// ---- hp[b][a] = hidden[b,:]·Wd[a,:] + bias[a]   (f32, tiny)
__global__ void k_hp(const float* __restrict__ hidden, const float* __restrict__ w,
                     const float* __restrict__ wbias, float* __restrict__ hp) {
  __shared__ float hs[1024];
  int b = blockIdx.x, tid = threadIdx.x;
  for (int i = tid; i < 1024; i += 256) hs[i] = hidden[b * 1024 + i];
  __syncthreads();
  int a = blockIdx.y * 256 + tid;
  const f4* wd = (const f4*)(w + a * 2048 + 1024);
  const f4* hv = (const f4*)hs;
  float acc = wbias[a];
  #pragma unroll 8
  for (int d = 0; d < 256; ++d) {
    f4 x = wd[d], y = hv[d];
    acc += x[0]*y[0] + x[1]*y[1] + x[2]*y[2] + x[3]*y[3];
  }
  hp[b * 1024 + a] = acc;
}

#define GLD16(gp, lp) __builtin_amdgcn_global_load_lds( \
    (const __attribute__((address_space(1))) void*)(gp), \
    (__attribute__((address_space(3))) void*)(lp), 16, 0, 0)

// ---- big fused GEMM: X = A(chunk of 131072x1024 bf16) * We^T, epilogue tanh(X+hp)·vw
// partials[p][b][s], p = bn*2 + wave_col  (16 partials of the a-reduction)
// bm0: global row-block offset of this chunk (in units of 128 rows)
__global__ __launch_bounds__(256) void k_gemm(
    const unsigned short* __restrict__ Avb, const unsigned short* __restrict__ Wb,
    const float* __restrict__ hp, const float* __restrict__ vw,
    float* __restrict__ part, int bm0) {
  __shared__ unsigned short lA[2][128 * 32];
  __shared__ unsigned short lB[2][128 * 32];
  int bid = blockIdx.x;
  // XCD swizzle: the 8 bn-blocks of one bm land on the same XCD within a 64-block window
  int bmL = ((bid >> 6) << 3) | (bid & 7);      // chunk-local row block
  int bn = (bid >> 3) & 7;
  int bm = bm0 + bmL;                           // global row block
  int tid = threadIdx.x, lane = tid & 63;
  int wid = tid >> 6, wr = wid >> 1, wc = wid & 1;

  // staging addresses (both operands via global_load_lds, pre-swizzled source)
  int si = tid, row_s = si >> 2, kqp = si & 3;
  int kql = kqp ^ (row_s & 3);
  const unsigned short* aS0 = Avb + (size_t)(bmL * 128 + row_s) * 1024 + kql * 8;
  const unsigned short* bS0 = Wb + (size_t)(bn * 128 + row_s) * 1024 + kql * 8;
  int si2 = tid + 256, row_s2 = si2 >> 2, kqp2 = si2 & 3;
  int kql2 = kqp2 ^ (row_s2 & 3);
  const unsigned short* aS1 = Avb + (size_t)(bmL * 128 + row_s2) * 1024 + kql2 * 8;
  const unsigned short* bS1 = Wb + (size_t)(bn * 128 + row_s2) * 1024 + kql2 * 8;

  f4 acc[4][4];
  f4 z = {0.f, 0.f, 0.f, 0.f};
  #pragma unroll
  for (int i = 0; i < 4; ++i)
    #pragma unroll
    for (int j = 0; j < 4; ++j) acc[i][j] = z;

  auto stage = [&](int buf, int t) {
    GLD16(aS0 + t * 32, &lA[buf][si * 8]);
    GLD16(bS0 + t * 32, &lB[buf][si * 8]);
    GLD16(aS1 + t * 32, &lA[buf][si2 * 8]);
    GLD16(bS1 + t * 32, &lB[buf][si2 * 8]);
  };
  auto compute = [&](int buf) {
    s8 af_[4], bf_[4];
    int kq = lane >> 4, c = lane & 15;
    #pragma unroll
    for (int mi = 0; mi < 4; ++mi) {
      int row = wr * 64 + mi * 16 + c;
      af_[mi] = *(const s8*)&lA[buf][row * 32 + ((kq ^ (row & 3)) << 3)];
    }
    #pragma unroll
    for (int ni = 0; ni < 4; ++ni) {
      int row = wc * 64 + ni * 16 + c;
      bf_[ni] = *(const s8*)&lB[buf][row * 32 + ((kq ^ (row & 3)) << 3)];
    }
    #pragma unroll
    for (int mi = 0; mi < 4; ++mi)
      #pragma unroll
      for (int ni = 0; ni < 4; ++ni)
        acc[mi][ni] = __builtin_amdgcn_mfma_f32_16x16x32_bf16(af_[mi], bf_[ni], acc[mi][ni], 0, 0, 0);
  };

  stage(0, 0);
  __syncthreads();
  for (int t = 0; t < 32; ++t) {
    int buf = t & 1;
    if (t < 31) stage(buf ^ 1, t + 1);
    compute(buf);
    __syncthreads();
  }

  // epilogue: e = tanh(x + hp[b][a]) * vw[a]; reduce over the 64 a-columns of this wave
  int c = lane & 15, lg = lane >> 4;
  int colBase = bn * 128 + wc * 64 + c;
  float rs[4][4];
  #pragma unroll
  for (int mi = 0; mi < 4; ++mi)
    #pragma unroll
    for (int j = 0; j < 4; ++j) rs[mi][j] = 0.f;
  #pragma unroll
  for (int ni = 0; ni < 4; ++ni) {
    int a = colBase + ni * 16;
    float vwa = vw[a];
    const float* hpa = hp + a;
    #pragma unroll
    for (int mi = 0; mi < 4; ++mi) {
      #pragma unroll
      for (int j = 0; j < 4; ++j) {
        int r = wr * 64 + mi * 16 + lg * 4 + j;
        int b = r & 63;                           // row%64 (bm*128 ≡ 0 mod 64)
        float x = acc[mi][ni][j] + hpa[b * 1024];
        rs[mi][j] += fast_tanh(x) * vwa;
      }
    }
  }
  #pragma unroll
  for (int off = 1; off < 16; off <<= 1) {
    #pragma unroll
    for (int mi = 0; mi < 4; ++mi)
      #pragma unroll
      for (int j = 0; j < 4; ++j)
        rs[mi][j] += __shfl_xor(rs[mi][j], off, 64);
  }
  if ((lane & 15) == 0) {
    int p = bn * 2 + wc;
    #pragma unroll
    for (int mi = 0; mi < 4; ++mi)
      #pragma unroll
      for (int j = 0; j < 4; ++j) {
        int m = bm * 128 + wr * 64 + mi * 16 + lg * 4 + j;
        int b = m & 63, s = m >> 6;
        part[(size_t)p * MT + b * SS + s] = rs[mi][j];
      }
  }
}

// ---- sum 16 partials -> scores, softmax over s per b -> weights[b][s]
__global__ void k_softmax(const float* __restrict__ part, float* __restrict__ wt) {
  int b = blockIdx.x, tid = threadIdx.x, lane = tid & 63, wid = tid >> 6;
  __shared__ float red[8];
  float sc[8];
  float mx = -1e30f;
  #pragma unroll
  for (int i = 0; i < 8; ++i) {
    int s = tid + i * 256;
    float a = 0.f;
    #pragma unroll
    for (int p = 0; p < 16; ++p) a += part[(size_t)p * MT + b * SS + s];
    sc[i] = a; mx = fmaxf(mx, a);
  }
  for (int o = 1; o < 64; o <<= 1) mx = fmaxf(mx, __shfl_xor(mx, o, 64));
  if (lane == 0) red[wid] = mx;
  __syncthreads();
  mx = fmaxf(fmaxf(red[0], red[1]), fmaxf(red[2], red[3]));
  float sum = 0.f;
  #pragma unroll
  for (int i = 0; i < 8; ++i) { sc[i] = expf(sc[i] - mx); sum += sc[i]; }
  for (int o = 1; o < 64; o <<= 1) sum += __shfl_xor(sum, o, 64);
  if (lane == 0) red[4 + wid] = sum;
  __syncthreads();
  sum = red[4] + red[5] + red[6] + red[7];
  float inv = 1.f / sum;
  #pragma unroll
  for (int i = 0; i < 8; ++i) wt[b * SS + tid + i * 256] = sc[i] * inv;
}

// ---- context partials from bf16 v: ctxp[cch][b][e] = sum_{s in chunk} w[b][s]*v[s][b][e]
__global__ void k_ctx_bf(const unsigned short* __restrict__ vb, const float* __restrict__ wt,
                         float* __restrict__ ctxp) {
  int b = blockIdx.x, cch = blockIdx.y, tid = threadIdx.x;
  f4 acc = {0.f, 0.f, 0.f, 0.f};
  int s0 = cch * 128;
  const float* wrow = wt + b * SS;
  #pragma unroll 4
  for (int s = s0; s < s0 + 128; ++s) {
    float ws = wrow[s];
    ushort4 u = *(const ushort4*)(vb + (size_t)(s * 64 + b) * 1024 + tid * 4);
    acc[0] += bf2f(u.x) * ws;
    acc[1] += bf2f(u.y) * ws;
    acc[2] += bf2f(u.z) * ws;
    acc[3] += bf2f(u.w) * ws;
  }
  *(f4*)(ctxp + (size_t)(cch * 64 + b) * 1024 + tid * 4) = acc;
}

// ---- context partials from f32 v (fallback when vb was chunk-overwritten)
__global__ void k_ctx_f32(const float* __restrict__ v, const float* __restrict__ wt,
                          float* __restrict__ ctxp) {
  int b = blockIdx.x, cch = blockIdx.y, tid = threadIdx.x;
  f4 acc = {0.f, 0.f, 0.f, 0.f};
  int s0 = cch * 128;
  const float* wrow = wt + b * SS;
  #pragma unroll 4
  for (int s = s0; s < s0 + 128; ++s) {
    float ws = wrow[s];
    const f4* vp = (const f4*)(v + (size_t)(s * 64 + b) * 1024);
    acc += vp[tid] * ws;
  }
  *(f4*)(ctxp + (size_t)(cch * 64 + b) * 1024 + tid * 4) = acc;
}

__global__ void k_out(const float* __restrict__ ctxp, float* __restrict__ out) {
  int b = blockIdx.x, tid = threadIdx.x;
  f4 acc = {0.f, 0.f, 0.f, 0.f};
  #pragma unroll
  for (int cch = 0; cch < 16; ++cch)
    acc += *(const f4*)(ctxp + (size_t)(cch * 64 + b) * 1024 + tid * 4);
  *(f4*)(out + b * 1024 + tid * 4) = acc;
}

extern "C" void kernel_launch(void* const* d_in, const int* in_sizes, int n_in,
                              void* d_out, int out_size, void* d_ws, size_t ws_size,
                              hipStream_t stream) {
  const float* hidden = (const float*)d_in[0];
  const float* v      = (const float*)d_in[1];   // (S, B, ENC) rows s*64+b
  const float* ww     = (const float*)d_in[2];   // (1024, 2048)
  const float* wbias  = (const float*)d_in[3];   // (1024)
  const float* vwgt   = (const float*)d_in[4];   // (1, 1024)
  // d_in[5] attn_v_bias: softmax shift-invariant, dropped
  float* out = (float*)d_out;

  char* ws = (char*)d_ws;
  float*          hp   = (float*)(ws);                                   // 256 KB
  unsigned short* wb   = (unsigned short*)(ws + 262144);                 // 2 MB
  float*          part = (float*)(ws + 262144 + 2097152);                // 8 MB
  float*          wt   = (float*)(ws + 262144 + 2097152 + 8388608);      // 512 KB
  float*          ctxp = (float*)(ws + 262144 + 2097152 + 8388608 + 524288); // 4 MB
  size_t fixed = 262144 + 2097152 + 8388608 + 524288 + 4194304;          // ~15.2 MB
  unsigned short* vb   = (unsigned short*)(ws + fixed);

  // chunk the A-conversion if workspace can't hold the full 256 MB bf16 copy
  size_t avail = (ws_size > fixed) ? (ws_size - fixed) : 0;
  long rows_chunk = (long)(avail / 2048) & ~1023L;     // bf16 row = 2048 B; multiple of 1024 rows
  if (rows_chunk > MT) rows_chunk = MT;
  if (rows_chunk < 1024) rows_chunk = 1024;            // hope ws is at least ~17 MB
  int nchunks = (int)((MT + rows_chunk - 1) / rows_chunk);

  k_convW<<<1024, 256, 0, stream>>>(ww, wb);
  k_hp<<<dim3(64, 4), 256, 0, stream>>>(hidden, ww, wbias, hp);

  for (long r0 = 0; r0 < MT; r0 += rows_chunk) {
    long nr = MT - r0; if (nr > rows_chunk) nr = rows_chunk;
    int convBlocks = (int)(nr * 1024 / 32768);
    k_convV<<<convBlocks, 256, 0, stream>>>(v, vb, (int)r0);
    int gemmBlocks = (int)(nr / 128) * 8;
    k_gemm<<<gemmBlocks, 256, 0, stream>>>(vb, wb, hp, vwgt, part, (int)(r0 / 128));
  }

  k_softmax<<<64, 256, 0, stream>>>(part, wt);
  if (nchunks == 1)
    k_ctx_bf<<<dim3(64, 16), 256, 0, stream>>>(vb, wt, ctxp);
  else
    k_ctx_f32<<<dim3(64, 16), 256, 0, stream>>>(v, wt, ctxp);
  k_out<<<64, 256, 0, stream>>>(ctxp, out);
}

// Round 3
// 630.902 us; speedup vs baseline: 1.6929x; 1.0116x over previous
//
#include <hip/hip_runtime.h>
#include <hip/hip_bf16.h>
#include <math.h>

#define BB 64
#define SS 2048
#define MT (SS*BB)   // 131072 rows of the big GEMM
#define NT 16        // K-tiles (K=1024, BK=64 per tile, 2 K-halves of 32)

typedef __attribute__((ext_vector_type(4))) float f4;
typedef __attribute__((ext_vector_type(8))) short s8;

__device__ __forceinline__ unsigned short f2bf(float x) {
  union { float f; unsigned u; } v; v.f = x;
  unsigned r = v.u + 0x7FFFu + ((v.u >> 16) & 1u);   // RNE
  return (unsigned short)(r >> 16);
}
__device__ __forceinline__ float bf2f(unsigned short x) {
  union { unsigned u; float f; } v; v.u = ((unsigned)x) << 16;
  return v.f;
}
__device__ __forceinline__ float fast_tanh(float x) {
  float t = __expf(2.0f * x);
  return 1.0f - 2.0f * __builtin_amdgcn_rcpf(t + 1.0f);
}

#define GLD16(gp, lp) __builtin_amdgcn_global_load_lds( \
    (const __attribute__((address_space(1))) void*)(gp), \
    (__attribute__((address_space(3))) void*)(lp), 16, 0, 0)
#define WAITV8() asm volatile("s_waitcnt vmcnt(8)" ::: "memory")
#define WAITV4() asm volatile("s_waitcnt vmcnt(4)" ::: "memory")
#define WAITV0() asm volatile("s_waitcnt vmcnt(0)" ::: "memory")
#define PBAR()   asm volatile("s_barrier" ::: "memory")

// ---- pack a 256-row x 64-col tile of a row-major f32 matrix into the
// swizzled bf16 tile layout the GEMM stages linearly:
// out[((tileIdx)*2 + kh)*8192 + r*32 + s*8 + j] = in[r][kt*64 + kh*32 + (s^((r>>1)&3))*8 + j]
__device__ __forceinline__ void pack_tile(const float* src, unsigned short* dst, int t) {
  int rsw = (t >> 1) & 3;
  #pragma unroll
  for (int kh = 0; kh < 2; ++kh) {
    #pragma unroll
    for (int s = 0; s < 4; ++s) {
      const float* sp = src + kh * 32 + (s ^ rsw) * 8;
      f4 x0 = *(const f4*)sp, x1 = *(const f4*)(sp + 4);
      s8 o;
      #pragma unroll
      for (int j = 0; j < 4; ++j) { o[j] = (short)f2bf(x0[j]); o[4 + j] = (short)f2bf(x1[j]); }
      *(s8*)(dst + kh * 8192 + s * 8) = o;
    }
  }
}

// grid (nrB, 16): block = (bmL, kt); thread t = row within the 256-row panel
__global__ void k_convV(const float* __restrict__ v, unsigned short* __restrict__ vbs, int r0) {
  int bmL = blockIdx.x, kt = blockIdx.y, t = threadIdx.x;
  const float* src = v + ((size_t)(r0 + bmL * 256 + t)) * 1024 + kt * 64;
  unsigned short* dst = vbs + ((size_t)(bmL * 16 + kt) * 2) * 8192 + t * 32;
  pack_tile(src, dst, t);
}

// grid (4, 16): block = (bn, kt); row = attention col a = bn*256 + t; source stride 2048
__global__ void k_convW(const float* __restrict__ w, unsigned short* __restrict__ wbs) {
  int bn = blockIdx.x, kt = blockIdx.y, t = threadIdx.x;
  const float* src = w + (size_t)(bn * 256 + t) * 2048 + kt * 64;
  unsigned short* dst = wbs + ((size_t)(bn * 16 + kt) * 2) * 8192 + t * 32;
  pack_tile(src, dst, t);
}

// ---- hp[b][a] = hidden[b,:]·Wd[a,:] + bias[a]
__global__ void k_hp(const float* __restrict__ hidden, const float* __restrict__ w,
                     const float* __restrict__ wbias, float* __restrict__ hp) {
  __shared__ float hs[1024];
  int b = blockIdx.x, tid = threadIdx.x;
  for (int i = tid; i < 1024; i += 256) hs[i] = hidden[b * 1024 + i];
  __syncthreads();
  int a = blockIdx.y * 256 + tid;
  const f4* wd = (const f4*)(w + a * 2048 + 1024);
  const f4* hv = (const f4*)hs;
  float acc = wbias[a];
  #pragma unroll 8
  for (int d = 0; d < 256; ++d) {
    f4 x = wd[d], y = hv[d];
    acc += x[0]*y[0] + x[1]*y[1] + x[2]*y[2] + x[3]*y[3];
  }
  hp[b * 1024 + a] = acc;
}

// ---- 8-phase-style fused GEMM: 256x256 tile, BK=64 (2 K-halves), 8 waves (2M x 4N),
// per-wave 128x64. Epilogue: tanh(x+hp)*vw reduced over the wave's 64 a-cols.
// partials[p][b][s], p = bn*4 + wc.
__global__ __launch_bounds__(512, 2) void k_gemm(
    const unsigned short* __restrict__ Avbs, const unsigned short* __restrict__ Wbs,
    const float* __restrict__ hp, const float* __restrict__ vw,
    float* __restrict__ part, int bm0, int nbm) {
  extern __shared__ char smem[];
  int bid = blockIdx.x;
  int nwg = nbm * 4;
  int wg = bid;
  if ((nwg & 7) == 0) { int cpx = nwg >> 3; wg = (bid & 7) * cpx + (bid >> 3); }
  int bn = wg / nbm;            // 0..3  (same-XCD chunk shares the B panel)
  int bmL = wg % nbm;
  int tid = threadIdx.x, lane = tid & 63;
  int wid = tid >> 6, wr = wid >> 2, wc = wid & 3;
  int c = lane & 15, kq = lane >> 4;

  // LDS frag addressing (bytes within a 16KB quarter region)
  int swz = kq ^ ((c >> 1) & 3);
  int a0 = (wr * 128 + c) * 64 + swz * 16;
  int b0 = (wc * 64 + c) * 64 + swz * 16;

  // stage: one unit (= A-or-B K-half quarter, 16KB) via 2x global_load_lds
  const unsigned short* Abase = Avbs + (size_t)bmL * 16 * 16384 + tid * 8;
  const unsigned short* Bbase = Wbs + (size_t)bn * 16 * 16384 + tid * 8;
  auto stage = [&](int tt, int cls) {
    int kh = cls >> 1;
    char* dst = smem + (tt & 1) * 65536 + cls * 16384 + tid * 16;
    const unsigned short* src = ((cls & 1) ? Bbase : Abase) + ((size_t)tt * 2 + kh) * 8192;
    GLD16(src, dst);
    GLD16(src + 4096, dst + 8192);
  };

  f4 acc[8][4];
  f4 z = {0.f, 0.f, 0.f, 0.f};
  #pragma unroll
  for (int i = 0; i < 8; ++i)
    #pragma unroll
    for (int j = 0; j < 4; ++j) acc[i][j] = z;

  // prologue: units 0..5 in order, then wait units 0,1 (tile0 kh0) done
  stage(0, 0); stage(0, 1); stage(0, 2); stage(0, 3); stage(1, 0); stage(1, 1);
  WAITV8();
  PBAR();

  s8 a[8];
  #pragma unroll 1
  for (int t = 0; t < NT; ++t) {
    const char* rb = smem + (t & 1) * 65536;
    #pragma unroll
    for (int p = 0; p < 4; ++p) {
      const int kh = p >> 1, q = p & 1;
      // stage one unit (lead 6): p0/p1 -> tile t+1 kh1 units; p2/p3 -> tile t+2 kh0 units
      if (p < 2) { if (t <= 14) stage(t + 1, 2 + p); }
      else       { if (t <= 13) stage(t + 2, p - 2); }
      // ds_read fragments for this phase
      const char* ra = rb + kh * 32768;
      const char* rbb = rb + 16384 + kh * 32768;
      if (q == 0) {
        #pragma unroll
        for (int mi = 0; mi < 8; ++mi) a[mi] = *(const s8*)(ra + a0 + mi * 1024);
      }
      s8 bf0 = *(const s8*)(rbb + b0 + (q * 2) * 1024);
      s8 bf1 = *(const s8*)(rbb + b0 + (q * 2 + 1) * 1024);
      PBAR();
      __builtin_amdgcn_s_setprio(1);
      #pragma unroll
      for (int mi = 0; mi < 8; ++mi) {
        acc[mi][q * 2]     = __builtin_amdgcn_mfma_f32_16x16x32_bf16(a[mi], bf0, acc[mi][q * 2], 0, 0, 0);
        acc[mi][q * 2 + 1] = __builtin_amdgcn_mfma_f32_16x16x32_bf16(a[mi], bf1, acc[mi][q * 2 + 1], 0, 0, 0);
      }
      __builtin_amdgcn_s_setprio(0);
      __builtin_amdgcn_sched_barrier(0);
      // counted waits guarding the NEXT phase's kh-half reads (never drain mid-loop)
      if (p == 1) { if (t < 15) WAITV8(); else WAITV0(); }
      if (p == 3) { if (t < 14) WAITV8(); else if (t == 14) WAITV4(); }
      PBAR();
    }
  }

  // epilogue: e = tanh(x + hp[b][a]) * vw[a]; reduce over this wave's 64 a-cols
  int lg = kq;
  int bm = bm0 + bmL;
  float rs[8][4];
  #pragma unroll
  for (int mi = 0; mi < 8; ++mi)
    #pragma unroll
    for (int j = 0; j < 4; ++j) rs[mi][j] = 0.f;
  #pragma unroll
  for (int ni = 0; ni < 4; ++ni) {
    int a_col = bn * 256 + wc * 64 + ni * 16 + c;
    float vwa = vw[a_col];
    const float* hpa = hp + a_col;
    #pragma unroll
    for (int mi = 0; mi < 8; ++mi) {
      #pragma unroll
      for (int j = 0; j < 4; ++j) {
        int r = wr * 128 + mi * 16 + lg * 4 + j;
        int b = r & 63;
        float x = acc[mi][ni][j] + hpa[b * 1024];
        rs[mi][j] += fast_tanh(x) * vwa;
      }
    }
  }
  #pragma unroll
  for (int off = 1; off < 16; off <<= 1) {
    #pragma unroll
    for (int mi = 0; mi < 8; ++mi)
      #pragma unroll
      for (int j = 0; j < 4; ++j)
        rs[mi][j] += __shfl_xor(rs[mi][j], off, 64);
  }
  if (c == 0) {
    int p = bn * 4 + wc;
    #pragma unroll
    for (int mi = 0; mi < 8; ++mi)
      #pragma unroll
      for (int j = 0; j < 4; ++j) {
        int m = bm * 256 + wr * 128 + mi * 16 + lg * 4 + j;
        int b = m & 63, s = m >> 6;
        part[(size_t)p * MT + b * SS + s] = rs[mi][j];
      }
  }
}

// ---- sum 16 partials -> scores, softmax over s per b -> weights[b][s]
__global__ void k_softmax(const float* __restrict__ part, float* __restrict__ wt) {
  int b = blockIdx.x, tid = threadIdx.x, lane = tid & 63, wid = tid >> 6;
  __shared__ float red[8];
  float sc[8];
  float mx = -1e30f;
  #pragma unroll
  for (int i = 0; i < 8; ++i) {
    int s = tid + i * 256;
    float a = 0.f;
    #pragma unroll
    for (int p = 0; p < 16; ++p) a += part[(size_t)p * MT + b * SS + s];
    sc[i] = a; mx = fmaxf(mx, a);
  }
  for (int o = 1; o < 64; o <<= 1) mx = fmaxf(mx, __shfl_xor(mx, o, 64));
  if (lane == 0) red[wid] = mx;
  __syncthreads();
  mx = fmaxf(fmaxf(red[0], red[1]), fmaxf(red[2], red[3]));
  float sum = 0.f;
  #pragma unroll
  for (int i = 0; i < 8; ++i) { sc[i] = expf(sc[i] - mx); sum += sc[i]; }
  for (int o = 1; o < 64; o <<= 1) sum += __shfl_xor(sum, o, 64);
  if (lane == 0) red[4 + wid] = sum;
  __syncthreads();
  sum = red[4] + red[5] + red[6] + red[7];
  float inv = 1.f / sum;
  #pragma unroll
  for (int i = 0; i < 8; ++i) wt[b * SS + tid + i * 256] = sc[i] * inv;
}

// ---- context from swizzled bf16 tiles: ctxp[cch][b][e] = sum_{s in chunk} w[b][s]*v[s][b][e]
__global__ void k_ctx_bfs(const unsigned short* __restrict__ vbs, const float* __restrict__ wt,
                          float* __restrict__ ctxp) {
  int b = blockIdx.x, cch = blockIdx.y, tid = threadIdx.x;
  int e = tid * 4;
  int kt = e >> 6, kh = (e >> 5) & 1, qo = (e >> 3) & 3, off = e & 7;
  f4 acc = {0.f, 0.f, 0.f, 0.f};
  int s0 = cch * 128;
  const float* wrow = wt + b * SS;
  #pragma unroll 4
  for (int s = s0; s < s0 + 128; ++s) {
    float ws = wrow[s];
    int row = s * 64 + b;
    int bmW = row >> 8, r = row & 255;
    size_t addr = ((size_t)(bmW * 16 + kt) * 2 + kh) * 8192 + r * 32 + ((qo ^ ((r >> 1) & 3)) << 3) + off;
    ushort4 u = *(const ushort4*)(vbs + addr);
    acc[0] += bf2f(u.x) * ws;
    acc[1] += bf2f(u.y) * ws;
    acc[2] += bf2f(u.z) * ws;
    acc[3] += bf2f(u.w) * ws;
  }
  *(f4*)(ctxp + (size_t)(cch * 64 + b) * 1024 + tid * 4) = acc;
}

// ---- context fallback from f32 v (used only when vbs was chunk-overwritten)
__global__ void k_ctx_f32(const float* __restrict__ v, const float* __restrict__ wt,
                          float* __restrict__ ctxp) {
  int b = blockIdx.x, cch = blockIdx.y, tid = threadIdx.x;
  f4 acc = {0.f, 0.f, 0.f, 0.f};
  int s0 = cch * 128;
  const float* wrow = wt + b * SS;
  #pragma unroll 4
  for (int s = s0; s < s0 + 128; ++s) {
    float ws = wrow[s];
    const f4* vp = (const f4*)(v + (size_t)(s * 64 + b) * 1024);
    acc += vp[tid] * ws;
  }
  *(f4*)(ctxp + (size_t)(cch * 64 + b) * 1024 + tid * 4) = acc;
}

__global__ void k_out(const float* __restrict__ ctxp, float* __restrict__ out) {
  int b = blockIdx.x, tid = threadIdx.x;
  f4 acc = {0.f, 0.f, 0.f, 0.f};
  #pragma unroll
  for (int cch = 0; cch < 16; ++cch)
    acc += *(const f4*)(ctxp + (size_t)(cch * 64 + b) * 1024 + tid * 4);
  *(f4*)(out + b * 1024 + tid * 4) = acc;
}

extern "C" void kernel_launch(void* const* d_in, const int* in_sizes, int n_in,
                              void* d_out, int out_size, void* d_ws, size_t ws_size,
                              hipStream_t stream) {
  const float* hidden = (const float*)d_in[0];
  const float* v      = (const float*)d_in[1];   // (S, B, ENC) rows s*64+b
  const float* ww     = (const float*)d_in[2];   // (1024, 2048)
  const float* wbias  = (const float*)d_in[3];   // (1024)
  const float* vwgt   = (const float*)d_in[4];   // (1, 1024)
  float* out = (float*)d_out;

  char* ws = (char*)d_ws;
  float*          hp   = (float*)(ws);                                   // 256 KB
  unsigned short* wbs  = (unsigned short*)(ws + 262144);                 // 2 MB (swizzled tiles)
  float*          part = (float*)(ws + 262144 + 2097152);                // 8 MB
  float*          wt   = (float*)(ws + 262144 + 2097152 + 8388608);      // 512 KB
  float*          ctxp = (float*)(ws + 262144 + 2097152 + 8388608 + 524288); // 4 MB
  size_t fixed = 262144 + 2097152 + 8388608 + 524288 + 4194304;          // ~15.2 MB
  unsigned short* vbs  = (unsigned short*)(ws + fixed);

  // chunk A-panel packing if ws can't hold the full 256 MB bf16 copy
  size_t avail = (ws_size > fixed) ? (ws_size - fixed) : 0;
  long rows_chunk = (long)(avail / 2048) & ~511L;      // multiple of 512 rows (2 bm-tiles)
  if (rows_chunk > MT) rows_chunk = MT;
  if (rows_chunk < 512) rows_chunk = 512;
  int nchunks = (int)((MT + rows_chunk - 1) / rows_chunk);

  hipFuncSetAttribute((const void*)k_gemm, hipFuncAttributeMaxDynamicSharedMemorySize, 131072);

  k_convW<<<dim3(4, 16), 256, 0, stream>>>(ww, wbs);
  k_hp<<<dim3(64, 4), 256, 0, stream>>>(hidden, ww, wbias, hp);

  for (long r0 = 0; r0 < MT; r0 += rows_chunk) {
    long nr = MT - r0; if (nr > rows_chunk) nr = rows_chunk;
    int nbm = (int)(nr / 256);
    k_convV<<<dim3(nbm, 16), 256, 0, stream>>>(v, vbs, (int)r0);
    k_gemm<<<nbm * 4, 512, 131072, stream>>>(vbs, wbs, hp, vwgt, part, (int)(r0 / 256), nbm);
  }

  k_softmax<<<64, 256, 0, stream>>>(part, wt);
  if (nchunks == 1)
    k_ctx_bfs<<<dim3(64, 16), 256, 0, stream>>>(vbs, wt, ctxp);
  else
    k_ctx_f32<<<dim3(64, 16), 256, 0, stream>>>(v, wt, ctxp);
  k_out<<<64, 256, 0, stream>>>(ctxp, out);
}

// Round 4
// 590.719 us; speedup vs baseline: 1.8080x; 1.0680x over previous
//
#include <hip/hip_runtime.h>
#include <hip/hip_bf16.h>
#include <math.h>

#define BB 64
#define SS 2048
#define MT (SS*BB)   // 131072 rows of the big GEMM
#define NTL 32       // K-tiles (K=1024, BK=32)

typedef __attribute__((ext_vector_type(4))) float f4;
typedef __attribute__((ext_vector_type(8))) short s8;

__device__ __forceinline__ unsigned short f2bf(float x) {
  union { float f; unsigned u; } v; v.f = x;
  unsigned r = v.u + 0x7FFFu + ((v.u >> 16) & 1u);   // RNE
  return (unsigned short)(r >> 16);
}
__device__ __forceinline__ float bf2f(unsigned short x) {
  union { unsigned u; float f; } v; v.u = ((unsigned)x) << 16;
  return v.f;
}
__device__ __forceinline__ float fast_tanh(float x) {
  float t = __expf(2.0f * x);
  return 1.0f - 2.0f * __builtin_amdgcn_rcpf(t + 1.0f);
}

#define GLD16(gp, lp) __builtin_amdgcn_global_load_lds( \
    (const __attribute__((address_space(1))) void*)(gp), \
    (__attribute__((address_space(3))) void*)(lp), 16, 0, 0)
#define WAITV4() asm volatile("s_waitcnt vmcnt(4)" ::: "memory")
#define WAITV0() asm volatile("s_waitcnt vmcnt(0)" ::: "memory")
#define BAR()    __builtin_amdgcn_s_barrier()

// ---- coalesced pack: f32 (rows x stride) -> swizzled bf16 tiles
// dst layout: [panel(256 rows)][kt(32 cols each)][row 0..255][slot s 0..3][8 shorts]
// where slot s holds source cols kt*32 + (s ^ ((row>>1)&3))*8 ..+8
// grid: (rows/64, 4); block 256
__global__ void k_pack(const float* __restrict__ src, unsigned short* __restrict__ dst,
                       int stride) {
  __shared__ float ls[64][260];
  int g = blockIdx.x, cb = blockIdx.y, tid = threadIdx.x;
  int cl = (tid & 63) * 4;
  int rb = tid >> 6;
  const float* s0 = src + (size_t)(g * 64) * stride + cb * 256 + cl;
  #pragma unroll
  for (int it = 0; it < 16; ++it) {
    int rr = it * 4 + rb;
    f4 x = *(const f4*)(s0 + (size_t)rr * stride);
    *(f4*)&ls[rr][cl] = x;
  }
  __syncthreads();
  int myKt = tid >> 5;              // 0..7
  int rr0 = (tid & 31) * 2;
  int panel = g >> 2;
  int prow0 = (g & 3) * 64 + rr0;
  #pragma unroll
  for (int rq = 0; rq < 2; ++rq) {
    int r = rr0 + rq, prow = prow0 + rq;
    int rsw = (prow >> 1) & 3;
    unsigned short* d = dst + (((size_t)panel * 32 + cb * 8 + myKt) * 256 + prow) * 32;
    #pragma unroll
    for (int s = 0; s < 4; ++s) {
      const float* sp = &ls[r][myKt * 32 + ((s ^ rsw) * 8)];
      f4 x0 = *(const f4*)sp, x1 = *(const f4*)(sp + 4);
      s8 o;
      #pragma unroll
      for (int j = 0; j < 4; ++j) { o[j] = (short)f2bf(x0[j]); o[4 + j] = (short)f2bf(x1[j]); }
      *(s8*)(d + s * 8) = o;
    }
  }
}

// ---- hp[b][a] = hidden[b,:]·Wd[a,:] + bias[a]
__global__ void k_hp(const float* __restrict__ hidden, const float* __restrict__ w,
                     const float* __restrict__ wbias, float* __restrict__ hp) {
  __shared__ float hs[1024];
  int b = blockIdx.x, tid = threadIdx.x;
  for (int i = tid; i < 1024; i += 256) hs[i] = hidden[b * 1024 + i];
  __syncthreads();
  int a = blockIdx.y * 256 + tid;
  const f4* wd = (const f4*)(w + a * 2048 + 1024);
  const f4* hv = (const f4*)hs;
  float acc = wbias[a];
  #pragma unroll 8
  for (int d = 0; d < 256; ++d) {
    f4 x = wd[d], y = hv[d];
    acc += x[0]*y[0] + x[1]*y[1] + x[2]*y[2] + x[3]*y[3];
  }
  hp[b * 1024 + a] = acc;
}

// ---- fused GEMM: 256x256 tile, BK=32, 8 waves (2M x 4N), per-wave 128x64.
// partials[p][b][s], p = bn*4 + wc.
__global__ __launch_bounds__(512, 2) void k_gemm(
    const unsigned short* __restrict__ Avbs, const unsigned short* __restrict__ Wbs,
    const float* __restrict__ hp, const float* __restrict__ vw,
    float* __restrict__ part, int bm0, int nbm) {
  extern __shared__ char smem[];
  int bid = blockIdx.x;
  int nwg = nbm * 4;
  int wg = bid;
  if ((nwg & 7) == 0) { int cpx = nwg >> 3; wg = (bid & 7) * cpx + (bid >> 3); }
  int bn = wg & 3;              // bn fastest: 4 readers of an A-tile sit on one XCD
  int bmL = wg >> 2;
  int tid = threadIdx.x, lane = tid & 63;
  int wid = tid >> 6, wr = wid >> 2, wc = wid & 3;
  int c = lane & 15, kq = lane >> 4;

  int swz = kq ^ ((c >> 1) & 3);
  int a0 = (wr * 128 + c) * 64 + swz * 16;     // byte offsets in a 16KB unit
  int b0 = (wc * 64 + c) * 64 + swz * 16;

  const unsigned short* Abase = Avbs + (size_t)bmL * 262144 + tid * 8;
  const unsigned short* Bbase = Wbs + (size_t)bn * 262144 + tid * 8;
  auto stageA = [&](int tt) {
    char* d = smem + (tt & 1) * 32768 + tid * 16;
    const unsigned short* s = Abase + (size_t)tt * 8192;
    GLD16(s, d); GLD16(s + 4096, d + 8192);
  };
  auto stageB = [&](int tt) {
    char* d = smem + (tt & 1) * 32768 + 16384 + tid * 16;
    const unsigned short* s = Bbase + (size_t)tt * 8192;
    GLD16(s, d); GLD16(s + 4096, d + 8192);
  };

  f4 acc[8][4];
  f4 z = {0.f, 0.f, 0.f, 0.f};
  #pragma unroll
  for (int i = 0; i < 8; ++i)
    #pragma unroll
    for (int j = 0; j < 4; ++j) acc[i][j] = z;

  stageA(0); stageB(0); stageA(1); stageB(1);
  WAITV4();
  BAR();

  s8 a[8];
  #pragma unroll 1
  for (int t = 0; t < NTL; ++t) {
    const char* ra = smem + (t & 1) * 32768;
    const char* rb = ra + 16384;
    // q0: A frags + B ni=0,1
    #pragma unroll
    for (int mi = 0; mi < 8; ++mi) a[mi] = *(const s8*)(ra + a0 + mi * 1024);
    s8 bf0 = *(const s8*)(rb + b0);
    s8 bf1 = *(const s8*)(rb + b0 + 1024);
    BAR();
    if (t <= 29) stageA(t + 2);          // A of tile t fully consumed
    __builtin_amdgcn_s_setprio(1);
    #pragma unroll
    for (int mi = 0; mi < 8; ++mi) {
      acc[mi][0] = __builtin_amdgcn_mfma_f32_16x16x32_bf16(a[mi], bf0, acc[mi][0], 0, 0, 0);
      acc[mi][1] = __builtin_amdgcn_mfma_f32_16x16x32_bf16(a[mi], bf1, acc[mi][1], 0, 0, 0);
    }
    __builtin_amdgcn_s_setprio(0);
    BAR();
    // q1: B ni=2,3
    s8 bf2 = *(const s8*)(rb + b0 + 2048);
    s8 bf3 = *(const s8*)(rb + b0 + 3072);
    BAR();
    if (t <= 29) stageB(t + 2);          // B of tile t fully consumed
    __builtin_amdgcn_s_setprio(1);
    #pragma unroll
    for (int mi = 0; mi < 8; ++mi) {
      acc[mi][2] = __builtin_amdgcn_mfma_f32_16x16x32_bf16(a[mi], bf2, acc[mi][2], 0, 0, 0);
      acc[mi][3] = __builtin_amdgcn_mfma_f32_16x16x32_bf16(a[mi], bf3, acc[mi][3], 0, 0, 0);
    }
    __builtin_amdgcn_s_setprio(0);
    if (t < 30) WAITV4();                // tile t+1 guaranteed landed
    else if (t == 30) WAITV0();
    BAR();
  }

  // epilogue: e = tanh(x + hp[b][a]) * vw[a]; reduce over this wave's 64 a-cols
  int lg = kq;
  int bm = bm0 + bmL;
  float rs[8][4];
  #pragma unroll
  for (int mi = 0; mi < 8; ++mi)
    #pragma unroll
    for (int j = 0; j < 4; ++j) rs[mi][j] = 0.f;
  #pragma unroll
  for (int ni = 0; ni < 4; ++ni) {
    int a_col = bn * 256 + wc * 64 + ni * 16 + c;
    float vwa = vw[a_col];
    const float* hpa = hp + a_col;
    #pragma unroll
    for (int mi = 0; mi < 8; ++mi) {
      #pragma unroll
      for (int j = 0; j < 4; ++j) {
        int r = wr * 128 + mi * 16 + lg * 4 + j;
        int b = r & 63;
        float x = acc[mi][ni][j] + hpa[b * 1024];
        rs[mi][j] += fast_tanh(x) * vwa;
      }
    }
  }
  #pragma unroll
  for (int off = 1; off < 16; off <<= 1) {
    #pragma unroll
    for (int mi = 0; mi < 8; ++mi)
      #pragma unroll
      for (int j = 0; j < 4; ++j)
        rs[mi][j] += __shfl_xor(rs[mi][j], off, 64);
  }
  if (c == 0) {
    int p = bn * 4 + wc;
    #pragma unroll
    for (int mi = 0; mi < 8; ++mi)
      #pragma unroll
      for (int j = 0; j < 4; ++j) {
        int m = bm * 256 + wr * 128 + mi * 16 + lg * 4 + j;
        int b = m & 63, s = m >> 6;
        part[(size_t)p * MT + b * SS + s] = rs[mi][j];
      }
  }
}

// ---- sum 16 partials -> scores, softmax over s per b -> weights[b][s]
__global__ void k_softmax(const float* __restrict__ part, float* __restrict__ wt) {
  int b = blockIdx.x, tid = threadIdx.x, lane = tid & 63, wid = tid >> 6;
  __shared__ float red[8];
  float sc[8];
  float mx = -1e30f;
  #pragma unroll
  for (int i = 0; i < 8; ++i) {
    int s = tid + i * 256;
    float a = 0.f;
    #pragma unroll
    for (int p = 0; p < 16; ++p) a += part[(size_t)p * MT + b * SS + s];
    sc[i] = a; mx = fmaxf(mx, a);
  }
  for (int o = 1; o < 64; o <<= 1) mx = fmaxf(mx, __shfl_xor(mx, o, 64));
  if (lane == 0) red[wid] = mx;
  __syncthreads();
  mx = fmaxf(fmaxf(red[0], red[1]), fmaxf(red[2], red[3]));
  float sum = 0.f;
  #pragma unroll
  for (int i = 0; i < 8; ++i) { sc[i] = expf(sc[i] - mx); sum += sc[i]; }
  for (int o = 1; o < 64; o <<= 1) sum += __shfl_xor(sum, o, 64);
  if (lane == 0) red[4 + wid] = sum;
  __syncthreads();
  sum = red[4] + red[5] + red[6] + red[7];
  float inv = 1.f / sum;
  #pragma unroll
  for (int i = 0; i < 8; ++i) wt[b * SS + tid + i * 256] = sc[i] * inv;
}

// ---- context from swizzled bf16 tiles
__global__ void k_ctx_bfs(const unsigned short* __restrict__ vbs, const float* __restrict__ wt,
                          float* __restrict__ ctxp) {
  int b = blockIdx.x, cch = blockIdx.y, tid = threadIdx.x;
  int e = tid * 4;
  int kt = e >> 5, qo = (e >> 3) & 3, off = e & 7;
  f4 acc = {0.f, 0.f, 0.f, 0.f};
  int s0 = cch * 128;
  const float* wrow = wt + b * SS;
  #pragma unroll 4
  for (int s = s0; s < s0 + 128; ++s) {
    float ws = wrow[s];
    int row = s * 64 + b;
    int bmW = row >> 8, r = row & 255;
    size_t addr = (((size_t)bmW * 32 + kt) * 256 + r) * 32 + ((qo ^ ((r >> 1) & 3)) << 3) + off;
    ushort4 u = *(const ushort4*)(vbs + addr);
    acc[0] += bf2f(u.x) * ws;
    acc[1] += bf2f(u.y) * ws;
    acc[2] += bf2f(u.z) * ws;
    acc[3] += bf2f(u.w) * ws;
  }
  *(f4*)(ctxp + (size_t)(cch * 64 + b) * 1024 + tid * 4) = acc;
}

// ---- context fallback from f32 v (multi-chunk only)
__global__ void k_ctx_f32(const float* __restrict__ v, const float* __restrict__ wt,
                          float* __restrict__ ctxp) {
  int b = blockIdx.x, cch = blockIdx.y, tid = threadIdx.x;
  f4 acc = {0.f, 0.f, 0.f, 0.f};
  int s0 = cch * 128;
  const float* wrow = wt + b * SS;
  #pragma unroll 4
  for (int s = s0; s < s0 + 128; ++s) {
    float ws = wrow[s];
    const f4* vp = (const f4*)(v + (size_t)(s * 64 + b) * 1024);
    acc += vp[tid] * ws;
  }
  *(f4*)(ctxp + (size_t)(cch * 64 + b) * 1024 + tid * 4) = acc;
}

__global__ void k_out(const float* __restrict__ ctxp, float* __restrict__ out) {
  int b = blockIdx.x, tid = threadIdx.x;
  f4 acc = {0.f, 0.f, 0.f, 0.f};
  #pragma unroll
  for (int cch = 0; cch < 16; ++cch)
    acc += *(const f4*)(ctxp + (size_t)(cch * 64 + b) * 1024 + tid * 4);
  *(f4*)(out + b * 1024 + tid * 4) = acc;
}

extern "C" void kernel_launch(void* const* d_in, const int* in_sizes, int n_in,
                              void* d_out, int out_size, void* d_ws, size_t ws_size,
                              hipStream_t stream) {
  const float* hidden = (const float*)d_in[0];
  const float* v      = (const float*)d_in[1];   // (S, B, ENC) rows s*64+b
  const float* ww     = (const float*)d_in[2];   // (1024, 2048)
  const float* wbias  = (const float*)d_in[3];   // (1024)
  const float* vwgt   = (const float*)d_in[4];   // (1, 1024)
  float* out = (float*)d_out;

  char* ws = (char*)d_ws;
  float*          hp   = (float*)(ws);                                   // 256 KB
  unsigned short* wbs  = (unsigned short*)(ws + 262144);                 // 2 MB
  float*          part = (float*)(ws + 262144 + 2097152);                // 8 MB
  float*          wt   = (float*)(ws + 262144 + 2097152 + 8388608);      // 512 KB
  float*          ctxp = (float*)(ws + 262144 + 2097152 + 8388608 + 524288); // 4 MB
  size_t fixed = 262144 + 2097152 + 8388608 + 524288 + 4194304;
  unsigned short* vbs  = (unsigned short*)(ws + fixed);

  size_t avail = (ws_size > fixed) ? (ws_size - fixed) : 0;
  long rows_chunk = (long)(avail / 2048) & ~511L;      // multiple of 512 rows
  if (rows_chunk > MT) rows_chunk = MT;
  if (rows_chunk < 512) rows_chunk = 512;
  int nchunks = (int)((MT + rows_chunk - 1) / rows_chunk);

  hipFuncSetAttribute((const void*)k_gemm, hipFuncAttributeMaxDynamicSharedMemorySize, 65536);

  k_pack<<<dim3(16, 4), 256, 0, stream>>>(ww, wbs, 2048);
  k_hp<<<dim3(64, 4), 256, 0, stream>>>(hidden, ww, wbias, hp);

  for (long r0 = 0; r0 < MT; r0 += rows_chunk) {
    long nr = MT - r0; if (nr > rows_chunk) nr = rows_chunk;
    int nbm = (int)(nr / 256);
    k_pack<<<dim3((int)(nr / 64), 4), 256, 0, stream>>>(v + (size_t)r0 * 1024, vbs, 1024);
    k_gemm<<<nbm * 4, 512, 65536, stream>>>(vbs, wbs, hp, vwgt, part, (int)(r0 / 256), nbm);
  }

  k_softmax<<<64, 256, 0, stream>>>(part, wt);
  if (nchunks == 1)
    k_ctx_bfs<<<dim3(64, 16), 256, 0, stream>>>(vbs, wt, ctxp);
  else
    k_ctx_f32<<<dim3(64, 16), 256, 0, stream>>>(v, wt, ctxp);
  k_out<<<64, 256, 0, stream>>>(ctxp, out);
}

// Round 5
// 586.576 us; speedup vs baseline: 1.8208x; 1.0071x over previous
//
#include <hip/hip_runtime.h>
#include <hip/hip_bf16.h>
#include <math.h>

#define BB 64
#define SS 2048
#define MT (SS*BB)   // 131072 rows of the big GEMM
#define NT 16        // K-tiles (K=1024, BK=64)

typedef __attribute__((ext_vector_type(4))) float f4;
typedef __attribute__((ext_vector_type(8))) short s8;

__device__ __forceinline__ unsigned short f2bf(float x) {
  union { float f; unsigned u; } v; v.f = x;
  unsigned r = v.u + 0x7FFFu + ((v.u >> 16) & 1u);   // RNE
  return (unsigned short)(r >> 16);
}
__device__ __forceinline__ float bf2f(unsigned short x) {
  union { unsigned u; float f; } v; v.u = ((unsigned)x) << 16;
  return v.f;
}
__device__ __forceinline__ float fast_tanh(float x) {
  float t = __expf(2.0f * x);
  return 1.0f - 2.0f * __builtin_amdgcn_rcpf(t + 1.0f);
}

#define GLD16(gp, lp) __builtin_amdgcn_global_load_lds( \
    (const __attribute__((address_space(1))) void*)(gp), \
    (__attribute__((address_space(3))) void*)(lp), 16, 0, 0)
#define WAITV4() asm volatile("s_waitcnt vmcnt(4)" ::: "memory")
#define WAITV2() asm volatile("s_waitcnt vmcnt(2)" ::: "memory")
#define WAITV0() asm volatile("s_waitcnt vmcnt(0)" ::: "memory")
#define BAR()    __builtin_amdgcn_s_barrier()

// ---- coalesced pack: f32 (rows x stride) -> swizzled bf16 units.
// Layout: [panel(256 rows)][kt 0..15][h=row>>7][r=row&127][8 slots x 8 shorts]
// where LDS-slot position s' at row r holds source cols kt*64 + (s'^(r&7))*8 ..+8.
// grid: (rows/64, 4); block 256.
__global__ void k_pack(const float* __restrict__ src, unsigned short* __restrict__ dst,
                       int stride) {
  __shared__ float ls[64][260];
  int g = blockIdx.x, cb = blockIdx.y, tid = threadIdx.x;
  int cl = (tid & 63) * 4, rbk = tid >> 6;
  const float* s0 = src + (size_t)(g * 64) * stride + cb * 256 + cl;
  #pragma unroll
  for (int it = 0; it < 16; ++it) {
    int rr = it * 4 + rbk;
    *(f4*)&ls[rr][cl] = *(const f4*)(s0 + (size_t)rr * stride);
  }
  __syncthreads();
  int kt_l = tid >> 6;              // 0..3
  int rr = tid & 63;
  int kt = cb * 4 + kt_l;
  int grow = g * 64 + rr;
  int panel = grow >> 8, pr = grow & 255, h = pr >> 7, r = pr & 127;
  unsigned short* d = dst + (((size_t)panel * 16 + kt) * 2 + h) * 8192 + r * 64;
  int rx = r & 7;
  #pragma unroll
  for (int sp = 0; sp < 8; ++sp) {
    const float* q = &ls[rr][kt_l * 64 + ((sp ^ rx) * 8)];
    f4 x0 = *(const f4*)q, x1 = *(const f4*)(q + 4);
    s8 o;
    #pragma unroll
    for (int j = 0; j < 4; ++j) { o[j] = (short)f2bf(x0[j]); o[4 + j] = (short)f2bf(x1[j]); }
    *(s8*)(d + sp * 8) = o;
  }
}

// ---- hp[b][a] = hidden[b,:]·Wd[a,:] + bias[a]
__global__ void k_hp(const float* __restrict__ hidden, const float* __restrict__ w,
                     const float* __restrict__ wbias, float* __restrict__ hp) {
  __shared__ float hs[1024];
  int b = blockIdx.x, tid = threadIdx.x;
  for (int i = tid; i < 1024; i += 256) hs[i] = hidden[b * 1024 + i];
  __syncthreads();
  int a = blockIdx.y * 256 + tid;
  const f4* wd = (const f4*)(w + a * 2048 + 1024);
  const f4* hv = (const f4*)hs;
  float acc = wbias[a];
  #pragma unroll 8
  for (int d = 0; d < 256; ++d) {
    f4 x = wd[d], y = hv[d];
    acc += x[0]*y[0] + x[1]*y[1] + x[2]*y[2] + x[3]*y[3];
  }
  hp[b * 1024 + a] = acc;
}

// ---- fused GEMM: 256x256 tile, BK=64, 8 waves (2M x 4N), per-wave 128x64.
// 4 phases per K-tile, one 16KB unit staged per phase, counted vmcnt(2)/K-tile.
// partials[p][b][s], p = bn*4 + wc.
__global__ __launch_bounds__(512, 2) void k_gemm(
    const unsigned short* __restrict__ Avbs, const unsigned short* __restrict__ Wbs,
    const float* __restrict__ hp, const float* __restrict__ vw,
    float* __restrict__ part, int bm0, int nbm) {
  extern __shared__ char smem[];
  int bid = blockIdx.x;
  int nwg = nbm * 4;
  int wg = bid;
  if ((nwg & 7) == 0) { int cpx = nwg >> 3; wg = (bid & 7) * cpx + (bid >> 3); }
  int bn = wg & 3;              // bn fastest: 4 readers of one A-tile on one XCD
  int bmL = wg >> 2;
  int tid = threadIdx.x, lane = tid & 63;
  int wid = tid >> 6, wr = wid >> 2, wc = wid & 3;
  int c = lane & 15, kq = lane >> 4;

  // slot byte offsets for ks=0/1 (8-slot XOR swizzle, row stride 128B)
  int sx0 = ((kq) ^ (c & 7)) << 4;
  int sx1 = ((4 + kq) ^ (c & 7)) << 4;
  int aoff = wr * 16384 + c * 128;                               // + mh*8192 + mi*2048 + sx
  int boff = 32768 + (wc >> 1) * 16384 + ((wc & 1) * 64 + c) * 128;  // + ni*2048 + sx

  const unsigned short* Abase = Avbs + (size_t)bmL * 262144 + tid * 8;
  const unsigned short* Bbase = Wbs + (size_t)bn * 262144 + tid * 8;
  auto stage = [&](int tt, int u) {   // u: 0=A-h0, 1=A-h1, 2=B-h0, 3=B-h1
    char* d = smem + (tt & 1) * 65536 + u * 16384 + tid * 16;
    const unsigned short* s = ((u & 2) ? Bbase : Abase) + ((size_t)tt * 2 + (u & 1)) * 8192;
    GLD16(s, d);
    GLD16(s + 4096, d + 8192);
  };

  f4 acc[8][4];
  f4 z = {0.f, 0.f, 0.f, 0.f};
  #pragma unroll
  for (int i = 0; i < 8; ++i)
    #pragma unroll
    for (int j = 0; j < 4; ++j) acc[i][j] = z;

  s8 va[4], vb0[4], vb1[4];

#define LDA(rb, mh, SX) { const char* ba_ = (rb) + aoff + (mh) * 8192 + (SX); \
    va[0] = *(const s8*)(ba_); va[1] = *(const s8*)(ba_ + 2048); \
    va[2] = *(const s8*)(ba_ + 4096); va[3] = *(const s8*)(ba_ + 6144); }
#define LDB(rb, VB, SX) { const char* bb_ = (rb) + boff + (SX); \
    VB[0] = *(const s8*)(bb_); VB[1] = *(const s8*)(bb_ + 2048); \
    VB[2] = *(const s8*)(bb_ + 4096); VB[3] = *(const s8*)(bb_ + 6144); }
#define MM(mh, VB) { \
    __builtin_amdgcn_s_setprio(1); \
    _Pragma("unroll") \
    for (int m_ = 0; m_ < 4; ++m_) { \
      acc[(mh)*4+m_][0] = __builtin_amdgcn_mfma_f32_16x16x32_bf16(va[m_], VB[0], acc[(mh)*4+m_][0], 0, 0, 0); \
      acc[(mh)*4+m_][1] = __builtin_amdgcn_mfma_f32_16x16x32_bf16(va[m_], VB[1], acc[(mh)*4+m_][1], 0, 0, 0); \
      acc[(mh)*4+m_][2] = __builtin_amdgcn_mfma_f32_16x16x32_bf16(va[m_], VB[2], acc[(mh)*4+m_][2], 0, 0, 0); \
      acc[(mh)*4+m_][3] = __builtin_amdgcn_mfma_f32_16x16x32_bf16(va[m_], VB[3], acc[(mh)*4+m_][3], 0, 0, 0); \
    } \
    __builtin_amdgcn_s_setprio(0); }

  // prologue: tile0 all 4 units, then B units of tile1 (12 loads)
  stage(0, 0); stage(0, 1); stage(0, 2); stage(0, 3);
  stage(1, 2); stage(1, 3);
  WAITV4();            // tile0's 4 units landed; B(1) may fly
  BAR();

  #pragma unroll 1
  for (int t = 0; t < NT; ++t) {
    const char* rb = smem + (t & 1) * 65536;
    // P0: reads A(mh0,ks0) + B(ks0); stage A-h0(t+1)
    LDA(rb, 0, sx0); LDB(rb, vb0, sx0);
    if (t < 15) stage(t + 1, 0);
    BAR();
    MM(0, vb0);
    BAR();
    // P1: reads A(mh0,ks1) + B(ks1); stage A-h1(t+1)
    LDA(rb, 0, sx1); LDB(rb, vb1, sx1);
    if (t < 15) stage(t + 1, 1);
    BAR();
    MM(0, vb1);
    BAR();
    // P2: reads A(mh1,ks0); stage B-h0(t+2)
    LDA(rb, 1, sx0);
    if (t < 14) stage(t + 2, 2);
    BAR();
    MM(1, vb0);
    BAR();
    // P3: reads A(mh1,ks1); stage B-h1(t+2)
    LDA(rb, 1, sx1);
    if (t < 14) stage(t + 2, 3);
    BAR();
    MM(1, vb1);
    if (t < 14) WAITV2();          // A(t+1) landed; B(t+2) pair may fly
    else if (t == 14) WAITV0();    // last A stages must land
    BAR();
  }
#undef LDA
#undef LDB
#undef MM

  // epilogue: e = tanh(x + hp[b][a]) * vw[a]; reduce over this wave's 64 a-cols
  int lg = kq;
  int bm = bm0 + bmL;
  float rs[8][4];
  #pragma unroll
  for (int mi = 0; mi < 8; ++mi)
    #pragma unroll
    for (int j = 0; j < 4; ++j) rs[mi][j] = 0.f;
  #pragma unroll
  for (int ni = 0; ni < 4; ++ni) {
    int a_col = bn * 256 + wc * 64 + ni * 16 + c;
    float vwa = vw[a_col];
    const float* hpa = hp + a_col;
    #pragma unroll
    for (int mi = 0; mi < 8; ++mi) {
      #pragma unroll
      for (int j = 0; j < 4; ++j) {
        int r = wr * 128 + mi * 16 + lg * 4 + j;
        int b = r & 63;
        float x = acc[mi][ni][j] + hpa[b * 1024];
        rs[mi][j] += fast_tanh(x) * vwa;
      }
    }
  }
  #pragma unroll
  for (int off = 1; off < 16; off <<= 1) {
    #pragma unroll
    for (int mi = 0; mi < 8; ++mi)
      #pragma unroll
      for (int j = 0; j < 4; ++j)
        rs[mi][j] += __shfl_xor(rs[mi][j], off, 64);
  }
  if (c == 0) {
    int p = bn * 4 + wc;
    #pragma unroll
    for (int mi = 0; mi < 8; ++mi)
      #pragma unroll
      for (int j = 0; j < 4; ++j) {
        int m = bm * 256 + wr * 128 + mi * 16 + lg * 4 + j;
        int b = m & 63, s = m >> 6;
        part[(size_t)p * MT + b * SS + s] = rs[mi][j];
      }
  }
}

// ---- sum 16 partials -> scores, softmax over s per b -> weights[b][s]
__global__ void k_softmax(const float* __restrict__ part, float* __restrict__ wt) {
  int b = blockIdx.x, tid = threadIdx.x, lane = tid & 63, wid = tid >> 6;
  __shared__ float red[8];
  float sc[8];
  float mx = -1e30f;
  #pragma unroll
  for (int i = 0; i < 8; ++i) {
    int s = tid + i * 256;
    float a = 0.f;
    #pragma unroll
    for (int p = 0; p < 16; ++p) a += part[(size_t)p * MT + b * SS + s];
    sc[i] = a; mx = fmaxf(mx, a);
  }
  for (int o = 1; o < 64; o <<= 1) mx = fmaxf(mx, __shfl_xor(mx, o, 64));
  if (lane == 0) red[wid] = mx;
  __syncthreads();
  mx = fmaxf(fmaxf(red[0], red[1]), fmaxf(red[2], red[3]));
  float sum = 0.f;
  #pragma unroll
  for (int i = 0; i < 8; ++i) { sc[i] = expf(sc[i] - mx); sum += sc[i]; }
  for (int o = 1; o < 64; o <<= 1) sum += __shfl_xor(sum, o, 64);
  if (lane == 0) red[4 + wid] = sum;
  __syncthreads();
  sum = red[4] + red[5] + red[6] + red[7];
  float inv = 1.f / sum;
  #pragma unroll
  for (int i = 0; i < 8; ++i) wt[b * SS + tid + i * 256] = sc[i] * inv;
}

// ---- context from swizzled bf16 units
__global__ void k_ctx_bfs(const unsigned short* __restrict__ vbs, const float* __restrict__ wt,
                          float* __restrict__ ctxp) {
  int b = blockIdx.x, cch = blockIdx.y, tid = threadIdx.x;
  int e = tid * 4;
  int kt = e >> 6, sl = (e >> 3) & 7, off = e & 7;
  f4 acc = {0.f, 0.f, 0.f, 0.f};
  int s0 = cch * 128;
  const float* wrow = wt + b * SS;
  #pragma unroll 4
  for (int s = s0; s < s0 + 128; ++s) {
    float ws = wrow[s];
    int row = s * 64 + b;
    int panel = row >> 8, pr = row & 255, h = pr >> 7, r = pr & 127;
    size_t addr = (((size_t)panel * 16 + kt) * 2 + h) * 8192 + r * 64 + ((sl ^ (r & 7)) << 3) + off;
    ushort4 u = *(const ushort4*)(vbs + addr);
    acc[0] += bf2f(u.x) * ws;
    acc[1] += bf2f(u.y) * ws;
    acc[2] += bf2f(u.z) * ws;
    acc[3] += bf2f(u.w) * ws;
  }
  *(f4*)(ctxp + (size_t)(cch * 64 + b) * 1024 + tid * 4) = acc;
}

// ---- context fallback from f32 v (multi-chunk only)
__global__ void k_ctx_f32(const float* __restrict__ v, const float* __restrict__ wt,
                          float* __restrict__ ctxp) {
  int b = blockIdx.x, cch = blockIdx.y, tid = threadIdx.x;
  f4 acc = {0.f, 0.f, 0.f, 0.f};
  int s0 = cch * 128;
  const float* wrow = wt + b * SS;
  #pragma unroll 4
  for (int s = s0; s < s0 + 128; ++s) {
    float ws = wrow[s];
    const f4* vp = (const f4*)(v + (size_t)(s * 64 + b) * 1024);
    acc += vp[tid] * ws;
  }
  *(f4*)(ctxp + (size_t)(cch * 64 + b) * 1024 + tid * 4) = acc;
}

__global__ void k_out(const float* __restrict__ ctxp, float* __restrict__ out) {
  int b = blockIdx.x, tid = threadIdx.x;
  f4 acc = {0.f, 0.f, 0.f, 0.f};
  #pragma unroll
  for (int cch = 0; cch < 16; ++cch)
    acc += *(const f4*)(ctxp + (size_t)(cch * 64 + b) * 1024 + tid * 4);
  *(f4*)(out + b * 1024 + tid * 4) = acc;
}

extern "C" void kernel_launch(void* const* d_in, const int* in_sizes, int n_in,
                              void* d_out, int out_size, void* d_ws, size_t ws_size,
                              hipStream_t stream) {
  const float* hidden = (const float*)d_in[0];
  const float* v      = (const float*)d_in[1];   // (S, B, ENC) rows s*64+b
  const float* ww     = (const float*)d_in[2];   // (1024, 2048)
  const float* wbias  = (const float*)d_in[3];   // (1024)
  const float* vwgt   = (const float*)d_in[4];   // (1, 1024)
  float* out = (float*)d_out;

  char* ws = (char*)d_ws;
  float*          hp   = (float*)(ws);                                   // 256 KB
  unsigned short* wbs  = (unsigned short*)(ws + 262144);                 // 2 MB
  float*          part = (float*)(ws + 262144 + 2097152);                // 8 MB
  float*          wt   = (float*)(ws + 262144 + 2097152 + 8388608);      // 512 KB
  float*          ctxp = (float*)(ws + 262144 + 2097152 + 8388608 + 524288); // 4 MB
  size_t fixed = 262144 + 2097152 + 8388608 + 524288 + 4194304;
  unsigned short* vbs  = (unsigned short*)(ws + fixed);

  size_t avail = (ws_size > fixed) ? (ws_size - fixed) : 0;
  long rows_chunk = (long)(avail / 2048) & ~511L;      // multiple of 512 rows
  if (rows_chunk > MT) rows_chunk = MT;
  if (rows_chunk < 512) rows_chunk = 512;
  int nchunks = (int)((MT + rows_chunk - 1) / rows_chunk);

  hipFuncSetAttribute((const void*)k_gemm, hipFuncAttributeMaxDynamicSharedMemorySize, 131072);

  k_pack<<<dim3(16, 4), 256, 0, stream>>>(ww, wbs, 2048);
  k_hp<<<dim3(64, 4), 256, 0, stream>>>(hidden, ww, wbias, hp);

  for (long r0 = 0; r0 < MT; r0 += rows_chunk) {
    long nr = MT - r0; if (nr > rows_chunk) nr = rows_chunk;
    int nbm = (int)(nr / 256);
    k_pack<<<dim3((int)(nr / 64), 4), 256, 0, stream>>>(v + (size_t)r0 * 1024, vbs, 1024);
    k_gemm<<<nbm * 4, 512, 131072, stream>>>(vbs, wbs, hp, vwgt, part, (int)(r0 / 256), nbm);
  }

  k_softmax<<<64, 256, 0, stream>>>(part, wt);
  if (nchunks == 1)
    k_ctx_bfs<<<dim3(64, 16), 256, 0, stream>>>(vbs, wt, ctxp);
  else
    k_ctx_f32<<<dim3(64, 16), 256, 0, stream>>>(v, wt, ctxp);
  k_out<<<64, 256, 0, stream>>>(ctxp, out);
}